// Round 3
// baseline (256.957 us; speedup 1.0000x reference)
//
#include <hip/hip_runtime.h>
#include <math.h>

#define Bn 16
#define Cn 3
#define Hn 512
#define Wn 512
#define HWn (Hn*Wn)          // 262144
#define CHWn (Cn*HWn)        // 786432
#define Rr 4                 // rows per wave strip

__device__ __forceinline__ float clamp01(float x) {
    return fminf(fmaxf(x, 0.0f), 1.0f);
}

// ---------------------------------------------------------------------------
// Kernel 1: per-batch sum of gray(input_ir), gray = .2989 R + .587 G + .114 B
// grid = (128, B), block = 256 -> 2048 blocks. Result into ws[b].
// ---------------------------------------------------------------------------
__global__ __launch_bounds__(256) void gray_mean_kernel(
        const float* __restrict__ ir, float* __restrict__ ws)
{
    const int b = blockIdx.y;
    const int tid = threadIdx.x;
    const float* base = ir + (size_t)b * CHWn;

    float sr = 0.f, sg = 0.f, sb = 0.f;
#pragma unroll
    for (int k = 0; k < 2; ++k) {
        size_t px = (size_t)blockIdx.x * 2048 + (size_t)(k * 256 + tid) * 4;
        float4 r4 = *(const float4*)(base + px);
        float4 g4 = *(const float4*)(base + HWn + px);
        float4 b4 = *(const float4*)(base + 2 * HWn + px);
        sr += (r4.x + r4.y) + (r4.z + r4.w);
        sg += (g4.x + g4.y) + (g4.z + g4.w);
        sb += (b4.x + b4.y) + (b4.z + b4.w);
    }
    float s = 0.2989f * sr + 0.587f * sg + 0.114f * sb;

#pragma unroll
    for (int off = 32; off; off >>= 1) s += __shfl_down(s, off, 64);

    __shared__ float red[4];
    if ((tid & 63) == 0) red[tid >> 6] = s;
    __syncthreads();
    if (tid == 0) atomicAdd(&ws[b], (red[0] + red[1]) + (red[2] + red[3]));
}

// ---------------------------------------------------------------------------
// Kernel 2: main fused kernel — FULL-ROW WAVES.
// One wave spans an entire 512-px row: lane l owns cols [8l, 8l+8).
// => stencil L/R neighbors are ALWAYS adjacent lanes: pure __shfl + cndmask,
//    no divergent edge loads, no interior boundaries, no branches.
// Wave w of a block owns rows [y0, y0+Rr), y0 = (blockIdx.x*4 + w)*Rr.
// grid = (Hn/(4*Rr), B) = (32,16) = 512 blocks.
// Accumulates into ws[16..20]: con, gx, gy, cr, cb sums.
// ---------------------------------------------------------------------------
__global__ __launch_bounds__(256, 2) void fusion_main_kernel(
        const float* __restrict__ vis, const float* __restrict__ ir,
        const float* __restrict__ outp, const float* __restrict__ mask,
        float* __restrict__ ws)
{
    const int tid  = threadIdx.x;
    const int lane = tid & 63;
    const int wv_id = tid >> 6;
    const int b    = blockIdx.y;
    const int y0   = (blockIdx.x * 4 + wv_id) * Rr;
    const int x0   = lane * 8;

    const float mean_b = ws[b] * (1.0f / (float)HWn);
    const float moff = 0.8f * mean_b;   // R_ir = clamp01(1.8*ir - moff)

    const size_t bb = (size_t)b * CHWn;
    const float* pv = vis  + bb;
    const float* pi = ir   + bb;
    const float* po = outp + bb;
    const float* pm = mask + bb;

    float conA = 0.f, gxA = 0.f, gyA = 0.f;

    // ---------------- per-channel sobel + intensity pass ----------------
    for (int c = 0; c < 3; ++c) {
        const float* v_ = pv + (size_t)c * HWn;
        const float* i_ = pi + (size_t)c * HWn;
        const float* o_ = po + (size_t)c * HWn;
        const float* m_ = pm + (size_t)c * HWn;

        // 3-row rotating window, 10 cols: [0]=x0-1, [1..8]=x0..x0+7, [9]=x0+8
        float wf[3][10], wvv[3][10], wi[3][10];

        auto load_row = [&](int y, int s) {
            if ((unsigned)y < (unsigned)Hn) {
                size_t o = (size_t)y * Wn + x0;
                float4 oa = *(const float4*)(o_ + o);
                float4 ob = *(const float4*)(o_ + o + 4);
                float4 ma = *(const float4*)(m_ + o);
                float4 mb = *(const float4*)(m_ + o + 4);
                float4 va = *(const float4*)(v_ + o);
                float4 vb = *(const float4*)(v_ + o + 4);
                float4 ia = *(const float4*)(i_ + o);
                float4 ib = *(const float4*)(i_ + o + 4);

                float df0 = oa.x * ma.x, df1 = oa.y * ma.y;
                float df2 = oa.z * ma.z, df3 = oa.w * ma.w;
                float df4 = ob.x * mb.x, df5 = ob.y * mb.y;
                float df6 = ob.z * mb.z, df7 = ob.w * mb.w;

                float dv0 = clamp01(sqrtf(va.x)), dv1 = clamp01(sqrtf(va.y));
                float dv2 = clamp01(sqrtf(va.z)), dv3 = clamp01(sqrtf(va.w));
                float dv4 = clamp01(sqrtf(vb.x)), dv5 = clamp01(sqrtf(vb.y));
                float dv6 = clamp01(sqrtf(vb.z)), dv7 = clamp01(sqrtf(vb.w));

                float di0 = clamp01(fmaf(1.8f, ia.x, -moff));
                float di1 = clamp01(fmaf(1.8f, ia.y, -moff));
                float di2 = clamp01(fmaf(1.8f, ia.z, -moff));
                float di3 = clamp01(fmaf(1.8f, ia.w, -moff));
                float di4 = clamp01(fmaf(1.8f, ib.x, -moff));
                float di5 = clamp01(fmaf(1.8f, ib.y, -moff));
                float di6 = clamp01(fmaf(1.8f, ib.z, -moff));
                float di7 = clamp01(fmaf(1.8f, ib.w, -moff));

                // neighbors from adjacent lanes; image edges -> derived 0
                float lf = __shfl_up(df7, 1, 64);
                float lv = __shfl_up(dv7, 1, 64);
                float li = __shfl_up(di7, 1, 64);
                float rf = __shfl_down(df0, 1, 64);
                float rv = __shfl_down(dv0, 1, 64);
                float ri = __shfl_down(di0, 1, 64);
                lf = (lane == 0)  ? 0.f : lf;
                lv = (lane == 0)  ? 0.f : lv;
                li = (lane == 0)  ? 0.f : li;
                rf = (lane == 63) ? 0.f : rf;
                rv = (lane == 63) ? 0.f : rv;
                ri = (lane == 63) ? 0.f : ri;

                wf[s][0] = lf;  wf[s][1] = df0; wf[s][2] = df1; wf[s][3] = df2;
                wf[s][4] = df3; wf[s][5] = df4; wf[s][6] = df5; wf[s][7] = df6;
                wf[s][8] = df7; wf[s][9] = rf;
                wvv[s][0] = lv;  wvv[s][1] = dv0; wvv[s][2] = dv1; wvv[s][3] = dv2;
                wvv[s][4] = dv3; wvv[s][5] = dv4; wvv[s][6] = dv5; wvv[s][7] = dv6;
                wvv[s][8] = dv7; wvv[s][9] = rv;
                wi[s][0] = li;  wi[s][1] = di0; wi[s][2] = di1; wi[s][3] = di2;
                wi[s][4] = di3; wi[s][5] = di4; wi[s][6] = di5; wi[s][7] = di6;
                wi[s][8] = di7; wi[s][9] = ri;
            } else {
#pragma unroll
                for (int k = 0; k < 10; ++k) { wf[s][k] = 0.f; wvv[s][k] = 0.f; wi[s][k] = 0.f; }
            }
        };

        // rows y0-1+k -> slot k%3
        load_row(y0 - 1, 0);
        load_row(y0,     1);

#pragma unroll
        for (int yy = 0; yy < Rr; ++yy) {
            const int st = yy % 3;         // row y-1
            const int sm = (yy + 1) % 3;   // row y
            const int sb = (yy + 2) % 3;   // row y+1
            load_row(y0 + yy + 1, sb);

#pragma unroll
            for (int j = 0; j < 8; ++j) {
                // cross-correlation (XLA conv): no kernel flip.
                float gxf = (wf[st][j+2] - wf[st][j]) + 2.f * (wf[sm][j+2] - wf[sm][j]) + (wf[sb][j+2] - wf[sb][j]);
                float gyf = (wf[st][j] + 2.f * wf[st][j+1] + wf[st][j+2]) - (wf[sb][j] + 2.f * wf[sb][j+1] + wf[sb][j+2]);

                float gxv = (wvv[st][j+2] - wvv[st][j]) + 2.f * (wvv[sm][j+2] - wvv[sm][j]) + (wvv[sb][j+2] - wvv[sb][j]);
                float gyv = (wvv[st][j] + 2.f * wvv[st][j+1] + wvv[st][j+2]) - (wvv[sb][j] + 2.f * wvv[sb][j+1] + wvv[sb][j+2]);

                float gxi = (wi[st][j+2] - wi[st][j]) + 2.f * (wi[sm][j+2] - wi[sm][j]) + (wi[sb][j+2] - wi[sb][j]);
                float gyi = (wi[st][j] + 2.f * wi[st][j+1] + wi[st][j+2]) - (wi[sb][j] + 2.f * wi[sb][j+1] + wi[sb][j+2]);

                gxA  += fabsf(gxf - fmaxf(gxv, gxi));
                gyA  += fabsf(gyf - fmaxf(gyv, gyi));
                conA += fabsf(wf[sm][j+1] - fmaxf(wvv[sm][j+1], wi[sm][j+1]));
            }
        }
    }

    // ---------------- color pass (center pixels, all 3 channels; L2-warm) ----
    float crA = 0.f, cbA = 0.f;
    {
        auto px4 = [&](float4 fR, float4 fG, float4 fB,
                       float4 vR, float4 vG, float4 vB) {
            auto one = [&](float fr, float fg, float fb, float vr, float vg, float vb) {
                float fY = 0.299f * fr + 0.587f * fg + 0.114f * fb;
                float vY = 0.299f * vr + 0.587f * vg + 0.114f * vb;
                crA += fabsf((fr - fY) - (vr - vY)) * 0.713f;
                cbA += fabsf((fb - fY) - (vb - vY)) * 0.564f;
            };
            one(fR.x, fG.x, fB.x, vR.x, vG.x, vB.x);
            one(fR.y, fG.y, fB.y, vR.y, vG.y, vB.y);
            one(fR.z, fG.z, fB.z, vR.z, vG.z, vB.z);
            one(fR.w, fG.w, fB.w, vR.w, vG.w, vB.w);
        };
#pragma unroll
        for (int yy = 0; yy < Rr; ++yy) {
#pragma unroll
            for (int h = 0; h < 2; ++h) {
                size_t o = (size_t)(y0 + yy) * Wn + x0 + 4 * h;
                float4 oR = *(const float4*)(po + o);
                float4 oG = *(const float4*)(po + HWn + o);
                float4 oB = *(const float4*)(po + 2 * HWn + o);
                float4 mR = *(const float4*)(pm + o);
                float4 mG = *(const float4*)(pm + HWn + o);
                float4 mB = *(const float4*)(pm + 2 * HWn + o);
                float4 vR = *(const float4*)(pv + o);
                float4 vG = *(const float4*)(pv + HWn + o);
                float4 vB = *(const float4*)(pv + 2 * HWn + o);
                float4 fR = make_float4(oR.x*mR.x, oR.y*mR.y, oR.z*mR.z, oR.w*mR.w);
                float4 fG = make_float4(oG.x*mG.x, oG.y*mG.y, oG.z*mG.z, oG.w*mG.w);
                float4 fB = make_float4(oB.x*mB.x, oB.y*mB.y, oB.z*mB.z, oB.w*mB.w);
                float4 rV = make_float4(clamp01(sqrtf(vR.x)), clamp01(sqrtf(vR.y)),
                                        clamp01(sqrtf(vR.z)), clamp01(sqrtf(vR.w)));
                float4 gV = make_float4(clamp01(sqrtf(vG.x)), clamp01(sqrtf(vG.y)),
                                        clamp01(sqrtf(vG.z)), clamp01(sqrtf(vG.w)));
                float4 bV = make_float4(clamp01(sqrtf(vB.x)), clamp01(sqrtf(vB.y)),
                                        clamp01(sqrtf(vB.z)), clamp01(sqrtf(vB.w)));
                px4(fR, fG, fB, rV, gV, bV);
            }
        }
    }

    // ---------------- block reduction + atomics ----------------
    auto wred = [](float x) {
#pragma unroll
        for (int off = 32; off; off >>= 1) x += __shfl_down(x, off, 64);
        return x;
    };
    conA = wred(conA); gxA = wred(gxA); gyA = wred(gyA);
    crA  = wred(crA);  cbA = wred(cbA);

    __shared__ float red[5][4];
    if (lane == 0) {
        red[0][wv_id] = conA; red[1][wv_id] = gxA; red[2][wv_id] = gyA;
        red[3][wv_id] = crA;  red[4][wv_id] = cbA;
    }
    __syncthreads();
    if (tid < 5) {
        float s = (red[tid][0] + red[tid][1]) + (red[tid][2] + red[tid][3]);
        atomicAdd(&ws[16 + tid], s);
    }
}

// ---------------------------------------------------------------------------
// Kernel 3: finalize scalar loss.
// loss = 0.5*con + 0.2*(0.5*gx + 0.5*gy) + (cb + cr)
// ---------------------------------------------------------------------------
__global__ void finalize_kernel(const float* __restrict__ ws, float* __restrict__ out)
{
    if (threadIdx.x == 0 && blockIdx.x == 0) {
        const float invN3 = 1.0f / (float)((size_t)Bn * Cn * HWn);
        const float invN1 = 1.0f / (float)((size_t)Bn * HWn);
        float con = ws[16] * invN3;
        float gx  = ws[17] * invN3;
        float gy  = ws[18] * invN3;
        float cr  = ws[19] * invN1;
        float cb  = ws[20] * invN1;
        out[0] = 0.5f * con + 0.2f * (0.5f * gx + 0.5f * gy) + (cb + cr);
    }
}

extern "C" void kernel_launch(void* const* d_in, const int* in_sizes, int n_in,
                              void* d_out, int out_size, void* d_ws, size_t ws_size,
                              hipStream_t stream)
{
    const float* vis = (const float*)d_in[0];
    const float* ir  = (const float*)d_in[1];
    const float* out = (const float*)d_in[2];
    const float* msk = (const float*)d_in[3];
    float* ws = (float*)d_ws;

    // ws[0..15] = per-batch gray sums; ws[16..20] = loss accumulators
    hipMemsetAsync(ws, 0, 32 * sizeof(float), stream);

    gray_mean_kernel<<<dim3(128, Bn), 256, 0, stream>>>(ir, ws);
    fusion_main_kernel<<<dim3(Hn / (4 * Rr), Bn), 256, 0, stream>>>(vis, ir, out, msk, ws);
    finalize_kernel<<<1, 64, 0, stream>>>(ws, (float*)d_out);
}

// Round 4
// 248.751 us; speedup vs baseline: 1.0330x; 1.0330x over previous
//
#include <hip/hip_runtime.h>
#include <math.h>

#define Bn 16
#define Cn 3
#define Hn 512
#define Wn 512
#define HWn (Hn*Wn)          // 262144
#define CHWn (Cn*HWn)        // 786432
#define Rr 8                 // rows per thread strip (R1's best value)

__device__ __forceinline__ float clamp01(float x) {
    return fminf(fmaxf(x, 0.0f), 1.0f);
}

// ---------------------------------------------------------------------------
// Kernel 1: per-batch sum of gray(input_ir), gray = .2989 R + .587 G + .114 B
// grid = (128, B), block = 256 -> 2048 blocks. Result into ws[b].
// ---------------------------------------------------------------------------
__global__ __launch_bounds__(256) void gray_mean_kernel(
        const float* __restrict__ ir, float* __restrict__ ws)
{
    const int b = blockIdx.y;
    const int tid = threadIdx.x;
    const float* base = ir + (size_t)b * CHWn;

    float sr = 0.f, sg = 0.f, sb = 0.f;
#pragma unroll
    for (int k = 0; k < 2; ++k) {
        size_t px = (size_t)blockIdx.x * 2048 + (size_t)(k * 256 + tid) * 4;
        float4 r4 = *(const float4*)(base + px);
        float4 g4 = *(const float4*)(base + HWn + px);
        float4 b4 = *(const float4*)(base + 2 * HWn + px);
        sr += (r4.x + r4.y) + (r4.z + r4.w);
        sg += (g4.x + g4.y) + (g4.z + g4.w);
        sb += (b4.x + b4.y) + (b4.z + b4.w);
    }
    float s = 0.2989f * sr + 0.587f * sg + 0.114f * sb;

#pragma unroll
    for (int off = 32; off; off >>= 1) s += __shfl_down(s, off, 64);

    __shared__ float red[4];
    if ((tid & 63) == 0) red[tid >> 6] = s;
    __syncthreads();
    if (tid == 0) atomicAdd(&ws[b], (red[0] + red[1]) + (red[2] + red[3]));
}

// ---------------------------------------------------------------------------
// Kernel 2: main fused kernel — R1 structure, CHANNEL-SPLIT grid.
// grid = (Hn/(2*Rr), B, C) = (32,16,3) = 1536 blocks -> 6144 waves
// (3x R1's wave count at IDENTICAL per-wave loop structure / VGPR).
// Each block handles sobel+intensity for channel blockIdx.z only.
// The color pass (all 3 channels) is done by the block with z == x%3.
// Accumulates into ws[16..20]: con, gx, gy, cr, cb sums.
// ---------------------------------------------------------------------------
__global__ __launch_bounds__(256) void fusion_main_kernel(
        const float* __restrict__ vis, const float* __restrict__ ir,
        const float* __restrict__ outp, const float* __restrict__ mask,
        float* __restrict__ ws)
{
    const int tid = threadIdx.x;
    const int tx = tid & 127;
    const int sy = tid >> 7;
    const int b  = blockIdx.y;
    const int c  = blockIdx.z;
    const int y0 = (blockIdx.x * 2 + sy) * Rr;
    const int x0 = tx * 4;

    const float mean_b = ws[b] * (1.0f / (float)HWn);
    const float moff = 0.8f * mean_b;   // R_ir = clamp01(1.8*ir - moff)

    const size_t bb = (size_t)b * CHWn;
    const float* pv = vis  + bb;
    const float* pi = ir   + bb;
    const float* po = outp + bb;
    const float* pm = mask + bb;

    float conA = 0.f, gxA = 0.f, gyA = 0.f;

    // ---------------- sobel + intensity pass for channel c ----------------
    {
        const float* v_ = pv + (size_t)c * HWn;
        const float* i_ = pi + (size_t)c * HWn;
        const float* o_ = po + (size_t)c * HWn;
        const float* m_ = pm + (size_t)c * HWn;

        // sliding window: slot 0 = row y-1, 1 = row y, 2 = row y+1
        // 6 columns: x0-1 .. x0+4
        float wf[3][6], wv[3][6], wi[3][6];

        auto load_row = [&](int y, int s) {
            if ((unsigned)y < (unsigned)Hn) {
                size_t o = (size_t)y * Wn + x0;
                float4 o4 = *(const float4*)(o_ + o);
                float4 m4 = *(const float4*)(m_ + o);
                float4 v4 = *(const float4*)(v_ + o);
                float4 i4 = *(const float4*)(i_ + o);
                float oL = 0.f, mL = 0.f, vL = 0.f, iL = 0.f;
                float oR = 0.f, mR = 0.f, vR = 0.f, iR = 0.f;
                if (x0 > 0)      { oL = o_[o - 1]; mL = m_[o - 1]; vL = v_[o - 1]; iL = i_[o - 1]; }
                if (x0 + 4 < Wn) { oR = o_[o + 4]; mR = m_[o + 4]; vR = v_[o + 4]; iR = i_[o + 4]; }

                wf[s][0] = oL * mL;     wf[s][1] = o4.x * m4.x;
                wf[s][2] = o4.y * m4.y; wf[s][3] = o4.z * m4.z;
                wf[s][4] = o4.w * m4.w; wf[s][5] = oR * mR;

                wv[s][0] = clamp01(sqrtf(vL));   wv[s][1] = clamp01(sqrtf(v4.x));
                wv[s][2] = clamp01(sqrtf(v4.y)); wv[s][3] = clamp01(sqrtf(v4.z));
                wv[s][4] = clamp01(sqrtf(v4.w)); wv[s][5] = clamp01(sqrtf(vR));

                wi[s][0] = clamp01(fmaf(1.8f, iL,   -moff));
                wi[s][1] = clamp01(fmaf(1.8f, i4.x, -moff));
                wi[s][2] = clamp01(fmaf(1.8f, i4.y, -moff));
                wi[s][3] = clamp01(fmaf(1.8f, i4.z, -moff));
                wi[s][4] = clamp01(fmaf(1.8f, i4.w, -moff));
                wi[s][5] = clamp01(fmaf(1.8f, iR,   -moff));
                // OOB columns: source 0 -> derived value exactly 0, matching
                // the conv's zero padding of the derived planes.
                if (x0 == 0)       { wf[s][0] = 0.f; wv[s][0] = 0.f; wi[s][0] = 0.f; }
                if (x0 + 4 >= Wn)  { wf[s][5] = 0.f; wv[s][5] = 0.f; wi[s][5] = 0.f; }
            } else {
#pragma unroll
                for (int k = 0; k < 6; ++k) { wf[s][k] = 0.f; wv[s][k] = 0.f; wi[s][k] = 0.f; }
            }
        };

        load_row(y0 - 1, 0);
        load_row(y0,     1);

        for (int yy = 0; yy < Rr; ++yy) {
            load_row(y0 + yy + 1, 2);

#pragma unroll
            for (int j = 0; j < 4; ++j) {
                // cross-correlation (XLA conv): no kernel flip.
                float gxf = (wf[0][j+2] - wf[0][j]) + 2.f * (wf[1][j+2] - wf[1][j]) + (wf[2][j+2] - wf[2][j]);
                float gyf = (wf[0][j] + 2.f * wf[0][j+1] + wf[0][j+2]) - (wf[2][j] + 2.f * wf[2][j+1] + wf[2][j+2]);

                float gxv = (wv[0][j+2] - wv[0][j]) + 2.f * (wv[1][j+2] - wv[1][j]) + (wv[2][j+2] - wv[2][j]);
                float gyv = (wv[0][j] + 2.f * wv[0][j+1] + wv[0][j+2]) - (wv[2][j] + 2.f * wv[2][j+1] + wv[2][j+2]);

                float gxi = (wi[0][j+2] - wi[0][j]) + 2.f * (wi[1][j+2] - wi[1][j]) + (wi[2][j+2] - wi[2][j]);
                float gyi = (wi[0][j] + 2.f * wi[0][j+1] + wi[0][j+2]) - (wi[2][j] + 2.f * wi[2][j+1] + wi[2][j+2]);

                gxA  += fabsf(gxf - fmaxf(gxv, gxi));
                gyA  += fabsf(gyf - fmaxf(gyv, gyi));
                conA += fabsf(wf[1][j+1] - fmaxf(wv[1][j+1], wi[1][j+1]));
            }

#pragma unroll
            for (int k = 0; k < 6; ++k) {
                wf[0][k] = wf[1][k]; wf[1][k] = wf[2][k];
                wv[0][k] = wv[1][k]; wv[1][k] = wv[2][k];
                wi[0][k] = wi[1][k]; wi[1][k] = wi[2][k];
            }
        }
    }

    // ------- color pass (all 3 channels; only one z-block per (x,b) does it) -------
    float crA = 0.f, cbA = 0.f;
    if (c == (int)(blockIdx.x % 3u)) {
        auto px = [&](float fr, float fg, float fb, float vr, float vg, float vb) {
            float fY = 0.299f * fr + 0.587f * fg + 0.114f * fb;
            float vY = 0.299f * vr + 0.587f * vg + 0.114f * vb;
            float crf = (fr - fY) * 0.713f, crv = (vr - vY) * 0.713f;
            float cbf = (fb - fY) * 0.564f, cbv = (vb - vY) * 0.564f;
            crA += fabsf(crf - crv);
            cbA += fabsf(cbf - cbv);
        };
        for (int y = y0; y < y0 + Rr; ++y) {
            size_t o = (size_t)y * Wn + x0;
            float4 oR = *(const float4*)(po + o);
            float4 oG = *(const float4*)(po + HWn + o);
            float4 oB = *(const float4*)(po + 2 * HWn + o);
            float4 mR = *(const float4*)(pm + o);
            float4 mG = *(const float4*)(pm + HWn + o);
            float4 mB = *(const float4*)(pm + 2 * HWn + o);
            float4 vR = *(const float4*)(pv + o);
            float4 vG = *(const float4*)(pv + HWn + o);
            float4 vB = *(const float4*)(pv + 2 * HWn + o);
            px(oR.x * mR.x, oG.x * mG.x, oB.x * mB.x,
               clamp01(sqrtf(vR.x)), clamp01(sqrtf(vG.x)), clamp01(sqrtf(vB.x)));
            px(oR.y * mR.y, oG.y * mG.y, oB.y * mB.y,
               clamp01(sqrtf(vR.y)), clamp01(sqrtf(vG.y)), clamp01(sqrtf(vB.y)));
            px(oR.z * mR.z, oG.z * mG.z, oB.z * mB.z,
               clamp01(sqrtf(vR.z)), clamp01(sqrtf(vG.z)), clamp01(sqrtf(vB.z)));
            px(oR.w * mR.w, oG.w * mG.w, oB.w * mB.w,
               clamp01(sqrtf(vR.w)), clamp01(sqrtf(vG.w)), clamp01(sqrtf(vB.w)));
        }
    }

    // ---------------- block reduction + atomics ----------------
    auto wred = [](float x) {
#pragma unroll
        for (int off = 32; off; off >>= 1) x += __shfl_down(x, off, 64);
        return x;
    };
    conA = wred(conA); gxA = wred(gxA); gyA = wred(gyA);
    crA  = wred(crA);  cbA = wred(cbA);

    __shared__ float red[5][4];
    const int lane = tid & 63, w = tid >> 6;
    if (lane == 0) {
        red[0][w] = conA; red[1][w] = gxA; red[2][w] = gyA;
        red[3][w] = crA;  red[4][w] = cbA;
    }
    __syncthreads();
    if (tid < 5) {
        float s = (red[tid][0] + red[tid][1]) + (red[tid][2] + red[tid][3]);
        atomicAdd(&ws[16 + tid], s);
    }
}

// ---------------------------------------------------------------------------
// Kernel 3: finalize scalar loss.
// loss = 0.5*con + 0.2*(0.5*gx + 0.5*gy) + (cb + cr)
// ---------------------------------------------------------------------------
__global__ void finalize_kernel(const float* __restrict__ ws, float* __restrict__ out)
{
    if (threadIdx.x == 0 && blockIdx.x == 0) {
        const float invN3 = 1.0f / (float)((size_t)Bn * Cn * HWn);
        const float invN1 = 1.0f / (float)((size_t)Bn * HWn);
        float con = ws[16] * invN3;
        float gx  = ws[17] * invN3;
        float gy  = ws[18] * invN3;
        float cr  = ws[19] * invN1;
        float cb  = ws[20] * invN1;
        out[0] = 0.5f * con + 0.2f * (0.5f * gx + 0.5f * gy) + (cb + cr);
    }
}

extern "C" void kernel_launch(void* const* d_in, const int* in_sizes, int n_in,
                              void* d_out, int out_size, void* d_ws, size_t ws_size,
                              hipStream_t stream)
{
    const float* vis = (const float*)d_in[0];
    const float* ir  = (const float*)d_in[1];
    const float* out = (const float*)d_in[2];
    const float* msk = (const float*)d_in[3];
    float* ws = (float*)d_ws;

    // ws[0..15] = per-batch gray sums; ws[16..20] = loss accumulators
    hipMemsetAsync(ws, 0, 32 * sizeof(float), stream);

    gray_mean_kernel<<<dim3(128, Bn), 256, 0, stream>>>(ir, ws);
    fusion_main_kernel<<<dim3(Hn / (2 * Rr), Bn, Cn), 256, 0, stream>>>(vis, ir, out, msk, ws);
    finalize_kernel<<<1, 64, 0, stream>>>(ws, (float*)d_out);
}